// Round 4
// baseline (191.678 us; speedup 1.0000x reference)
//
#include <hip/hip_runtime.h>
#include <hip/hip_bf16.h>

// ---------------------------------------------------------------------------
// B=2, S=2048, D=768, H=12, Dh=64. M = B*S = 4096.
// R18: non-attn reverted to R15-proven config (R17's fused V^T scatter was
// net -3us: uncoalesced stride-4KB ushort4 stores). attn = R17 (defer-max)
// + ZERO-SHUFFLE PV: MFMA contracts over k-slots, so with a slot->key
// bijection applied identically to A (V) and B (P) operands, the PV
// B-operand is the lane's OWN post-softmax p[] values (pure packing, no
// LDS bounce, no cross-lane ops). Ps buffer deleted (LDS 40960->32768);
// V fragment = two 8B reads (4 lanes/bank, better than old b128's 8/bank).
// ---------------------------------------------------------------------------

typedef __attribute__((ext_vector_type(8))) short short8;   // 8 x bf16 (4 VGPR)
typedef __attribute__((ext_vector_type(4))) float float4e;  // 4 x fp32 acc

__device__ __forceinline__ ushort f2bf(float f) {
    union { float f; unsigned u; } v; v.f = f;
    unsigned r = v.u + 0x7FFF + ((v.u >> 16) & 1);
    return (ushort)(r >> 16);
}

// packed RNE fp32x2 -> bf16x2 (v_cvt_pk_bf16_f32); low 16 bits = first arg
__device__ __forceinline__ unsigned pk2bf(float a, float b) {
    float2 t; t.x = a; t.y = b;
    __hip_bfloat162 h = __float22bfloat162_rn(t);
    union { __hip_bfloat162 h; unsigned u; } cv; cv.h = h;
    return cv.u;
}

// async 16B global -> LDS; LDS dest = wave-uniform base + lane*16.
__device__ __forceinline__ void async_cp16(const ushort* g, ushort* l) {
    __builtin_amdgcn_global_load_lds(
        (const __attribute__((address_space(1))) unsigned int*)g,
        (__attribute__((address_space(3))) unsigned int*)l,
        16, 0, 0);
}

// ===========================================================================
// x [4096x768] fp32 -> bf16
// ===========================================================================
__global__ __launch_bounds__(256) void cast_f32_bf16(
    const float* __restrict__ in, ushort* __restrict__ out, int n4)
{
    int i = blockIdx.x * blockDim.x + threadIdx.x;
    if (i < n4) {
        float4 v = *(const float4*)&in[(size_t)i * 4];
        ushort4 o;
        o.x = f2bf(v.x); o.y = f2bf(v.y); o.z = f2bf(v.z); o.w = f2bf(v.w);
        *(ushort4*)&out[(size_t)i * 4] = o;
    }
}

// ===========================================================================
// All 4 weight transposes in one launch: z selects Wq/Wk/Wv/Wo.
// ===========================================================================
__global__ __launch_bounds__(256) void transpose_cast_w4(
    const float* __restrict__ W0, const float* __restrict__ W1,
    const float* __restrict__ W2, const float* __restrict__ W3,
    ushort* __restrict__ WtBase)
{
    __shared__ float t[64][65];
    const int z = blockIdx.z;
    const float* W = (z == 0) ? W0 : (z == 1) ? W1 : (z == 2) ? W2 : W3;
    ushort* Wt = WtBase + (size_t)z * (768u * 768u);

    const int tid = threadIdx.x;
    const int c  = tid & 63;
    const int rg = tid >> 6;
    const int k0 = blockIdx.y * 64, n0 = blockIdx.x * 64;
    #pragma unroll
    for (int r = 0; r < 16; ++r) {
        const int row = rg * 16 + r;
        t[row][c] = W[(size_t)(k0 + row) * 768 + n0 + c];
    }
    __syncthreads();
    #pragma unroll
    for (int r = 0; r < 16; ++r) {
        const int row = rg * 16 + r;
        Wt[(size_t)(n0 + row) * 768 + k0 + c] = f2bf(t[c][row]);
    }
}

// ===========================================================================
// V [4096x768] bf16 -> VT[b][h][d][s] bf16 (s-major per head).
// ===========================================================================
__global__ __launch_bounds__(256) void transpose_v(
    const ushort* __restrict__ Vb, ushort* __restrict__ VT)
{
    __shared__ ushort t[64][72];
    const int tid = threadIdx.x;
    const int b = blockIdx.z, h = blockIdx.y, s0 = blockIdx.x * 64;
    const int lr = tid >> 3;          // 0..31
    const int lc = (tid & 7) * 8;     // 0..56

    #pragma unroll
    for (int half = 0; half < 64; half += 32) {
        const int row = lr + half;
        *(uint4*)&t[row][lc] =
            *(const uint4*)&Vb[(size_t)(b * 2048 + s0 + row) * 768 + h * 64 + lc];
    }
    __syncthreads();
    #pragma unroll
    for (int half = 0; half < 64; half += 32) {
        const int d = lr + half;
        ushort tmp[8];
        #pragma unroll
        for (int i = 0; i < 8; ++i) tmp[i] = t[lc + i][d];
        *(uint4*)&VT[((size_t)(b * 12 + h) * 64 + d) * 2048 + s0 + lc] =
            *(const uint4*)tmp;
    }
}

// ===========================================================================
// Fused QKV GEMM: Out[M,2304] = x[M,768] @ [Wq|Wk|Wv]^T + [bq|bk|bv]
// 128x128 tile, BK=32, 4 waves 2x2, 16 accs/wave; m97-style async staging.
// ===========================================================================
__global__ __launch_bounds__(256) void gemm_qkv_fused(
    const ushort* __restrict__ A, const ushort* __restrict__ Bt,
    const float* __restrict__ bq, const float* __restrict__ bk,
    const float* __restrict__ bv, ushort* __restrict__ Outbase)
{
    constexpr int K = 768;
    __shared__ ushort As[128][32];   // unpadded: required by global_load_lds
    __shared__ ushort Bs[128][32];

    const int tid  = threadIdx.x;
    const int w    = tid >> 6;
    const int lane = tid & 63;
    const int l16  = lane & 15;
    const int quad = lane >> 4;
    const int wr   = (w >> 1) * 64;
    const int wc   = (w & 1) * 64;
    const int row0 = blockIdx.y * 128, col0 = blockIdx.x * 128;

    const int r4 = lane >> 2;
    const int c8 = (lane & 3) * 8;

    float4e acc[4][4];
    #pragma unroll
    for (int mi = 0; mi < 4; ++mi)
        #pragma unroll
        for (int ni = 0; ni < 4; ++ni) acc[mi][ni] = (float4e){0.f,0.f,0.f,0.f};

    for (int k0 = 0; k0 < K; k0 += 32) {
        #pragma unroll
        for (int i = 0; i < 2; ++i) {
            const int rr = w * 32 + i * 16;
            async_cp16(&A [(size_t)(row0 + rr + r4) * K + k0 + c8], &As[rr][0]);
            async_cp16(&Bt[(size_t)(col0 + rr + r4) * K + k0 + c8], &Bs[rr][0]);
        }
        __syncthreads();   // drains vmcnt -> staged data visible

        short8 af[4], bf[4];
        #pragma unroll
        for (int i = 0; i < 4; ++i) {
            af[i] = *(const short8*)&As[wr + i * 16 + l16][quad * 8];
            bf[i] = *(const short8*)&Bs[wc + i * 16 + l16][quad * 8];
        }
        #pragma unroll
        for (int mi = 0; mi < 4; ++mi)
            #pragma unroll
            for (int ni = 0; ni < 4; ++ni)
                acc[mi][ni] = __builtin_amdgcn_mfma_f32_16x16x32_bf16(
                    af[mi], bf[ni], acc[mi][ni], 0, 0, 0);
        __syncthreads();
    }

    const int seg = (col0 >= 1536) ? 2 : (col0 >= 768 ? 1 : 0);
    const float* bias = (seg == 0) ? bq : (seg == 1) ? bk : bv;
    const int ncol0 = col0 - seg * 768 + wc;
    ushort* outp = Outbase + (size_t)seg * (4096u * 768u);

    #pragma unroll
    for (int ni = 0; ni < 4; ++ni) {
        const int col = ncol0 + ni * 16 + l16;
        const float bs = bias[col];
        #pragma unroll
        for (int mi = 0; mi < 4; ++mi) {
            #pragma unroll
            for (int r = 0; r < 4; ++r) {
                const int row = row0 + wr + mi * 16 + quad * 4 + r;
                outp[(size_t)row * 768 + col] = f2bf(acc[mi][ni][r] + bs);
            }
        }
    }
}

// ===========================================================================
// Wo GEMM: C[4096,768](fp32) = ctx[4096,768] @ Wo^T + bo. 128x128 tile,
// register-prefetch staging.
// ===========================================================================
__global__ __launch_bounds__(256) void gemm_wo_128(
    const ushort* __restrict__ A, const ushort* __restrict__ Bt,
    const float* __restrict__ bias, float* __restrict__ Cout)
{
    constexpr int K = 768, N = 768;
    __shared__ ushort As[128][40];
    __shared__ ushort Bs[128][40];

    const int tid  = threadIdx.x;
    const int w    = tid >> 6;
    const int lane = tid & 63;
    const int l16  = lane & 15;
    const int quad = lane >> 4;
    const int wr   = (w >> 1) * 64;
    const int wc   = (w & 1) * 64;
    const int row0 = blockIdx.y * 128, col0 = blockIdx.x * 128;
    const int sr = tid >> 2, sc = (tid & 3) * 8;

    float4e acc[4][4];
    #pragma unroll
    for (int mi = 0; mi < 4; ++mi)
        #pragma unroll
        for (int ni = 0; ni < 4; ++ni) acc[mi][ni] = (float4e){0.f,0.f,0.f,0.f};

    uint4 a0 = *(const uint4*)&A [(size_t)(row0 + sr     ) * K + sc];
    uint4 a1 = *(const uint4*)&A [(size_t)(row0 + sr + 64) * K + sc];
    uint4 b0 = *(const uint4*)&Bt[(size_t)(col0 + sr     ) * K + sc];
    uint4 b1 = *(const uint4*)&Bt[(size_t)(col0 + sr + 64) * K + sc];

    for (int k0 = 0; k0 < K; k0 += 32) {
        *(uint4*)&As[sr     ][sc] = a0;
        *(uint4*)&As[sr + 64][sc] = a1;
        *(uint4*)&Bs[sr     ][sc] = b0;
        *(uint4*)&Bs[sr + 64][sc] = b1;
        __syncthreads();

        if (k0 + 32 < K) {
            const int kn = k0 + 32;
            a0 = *(const uint4*)&A [(size_t)(row0 + sr     ) * K + kn + sc];
            a1 = *(const uint4*)&A [(size_t)(row0 + sr + 64) * K + kn + sc];
            b0 = *(const uint4*)&Bt[(size_t)(col0 + sr     ) * K + kn + sc];
            b1 = *(const uint4*)&Bt[(size_t)(col0 + sr + 64) * K + kn + sc];
        }

        short8 af[4], bf[4];
        #pragma unroll
        for (int i = 0; i < 4; ++i) {
            af[i] = *(const short8*)&As[wr + i * 16 + l16][quad * 8];
            bf[i] = *(const short8*)&Bs[wc + i * 16 + l16][quad * 8];
        }
        #pragma unroll
        for (int mi = 0; mi < 4; ++mi)
            #pragma unroll
            for (int ni = 0; ni < 4; ++ni)
                acc[mi][ni] = __builtin_amdgcn_mfma_f32_16x16x32_bf16(
                    af[mi], bf[ni], acc[mi][ni], 0, 0, 0);
        __syncthreads();
    }

    #pragma unroll
    for (int ni = 0; ni < 4; ++ni) {
        const int col = col0 + wc + ni * 16 + l16;
        const float bs = bias[col];
        #pragma unroll
        for (int mi = 0; mi < 4; ++mi) {
            #pragma unroll
            for (int r = 0; r < 4; ++r) {
                const int row = row0 + wr + mi * 16 + quad * 4 + r;
                Cout[(size_t)row * N + col] = acc[mi][ni][r] + bs;
            }
        }
    }
}

// ===========================================================================
// Flash attention, S^T form, intra-block split-K. 512 threads = 8 waves.
// Wave w: query group wq = w&3 (16 queries), key-half koff = (w>>2)*32.
// Pipeline per tile (R15-proven): issue DMA for t+1 -> compute t -> one
// __syncthreads (implicit vmcnt(0) drain). Rule-21 XOR swizzle on stage
// buffers. Defer-max (T13, THR=8). R18: zero-shuffle PV -- slot->key
// bijection sigma(quad, j<4) = koff+quad*4+j, sigma(quad, j>=4) =
// koff+16+quad*4+(j-4), applied to BOTH PV operands: B = own p[] packed,
// A = two 8B V reads per db. No Ps buffer. LDS = 32 KB.
// ===========================================================================
__global__ __launch_bounds__(512) void attn_mfma(
    const ushort* __restrict__ Qg, const ushort* __restrict__ Kgl,
    const ushort* __restrict__ VT, ushort* __restrict__ Ctx)
{
    constexpr int S = 2048, D = 768;
    __shared__ union {
        struct {                       // main-loop stage buffers (swizzled)
            ushort Ks [2][64][64];     // [buf][key][dblk^(key&7)]
            ushort Vts[2][64][64];     // [buf][d][keyblk^(d&7)]
        } s;
        struct {                       // epilogue combine buffers
            float Osc[4][16][68];
            float Msc[4][16], Lsc[4][16];
        } c;
    } U;

    const int tid  = threadIdx.x;
    const int w    = tid >> 6;        // 0..7
    const int wq   = w & 3;           // query group
    const int koff = (w >> 2) * 32;   // key-half within tile
    const int lane = tid & 63;
    const int l16  = lane & 15;
    const int quad = lane >> 4;
    const int b = blockIdx.z, h = blockIdx.y, q0 = blockIdx.x * 64;
    const size_t hc = (size_t)h * 64;

    // Q fragments, held in registers for the whole kernel
    const size_t qoff = (size_t)(b * S + q0 + wq * 16 + l16) * D + hc + quad * 8;
    const short8 yq0 = *(const short8*)&Qg[qoff];
    const short8 yq1 = *(const short8*)&Qg[qoff + 32];

    // ---- staging: 512 threads x 16B per matrix per tile; source address
    // pre-swizzled so the linear global_load_lds write lands XOR-swizzled.
    const int sr  = tid >> 3;                  // row 0..63
    const int cbg = (tid & 7) ^ (sr & 7);      // swizzled source col-block
    const ushort* srcK = &Kgl[(size_t)(b * S + sr) * D + hc + cbg * 8];
    const ushort* srcV = &VT[((size_t)(b * 12 + h) * 64 + sr) * 2048 + cbg * 8];
    ushort* dstK0 = &U.s.Ks [0][w * 8][0];     // wave-uniform bases
    ushort* dstK1 = &U.s.Ks [1][w * 8][0];
    ushort* dstV0 = &U.s.Vts[0][w * 8][0];
    ushort* dstV1 = &U.s.Vts[1][w * 8][0];

    // ---- loop-invariant swizzled read offsets (ushort units) ----
    int oxk[2][2];
    #pragma unroll
    for (int kb = 0; kb < 2; ++kb) {
        const int krow = koff + kb * 16 + l16;
        oxk[kb][0] = krow * 64 + (( quad     ) ^ (krow & 7)) * 8;
        oxk[kb][1] = krow * 64 + (((quad | 4)) ^ (krow & 7)) * 8;
    }
    // V reads (zero-shuffle PV): 8B granule view of the same layout,
    // pos8 = g8 ^ (2*(d&7)); g8 = koff/4 + kb*4 + quad. d = db*16+l16 ->
    // d&7 == l16&7, so db only adds db*1024 to the ushort offset.
    const int oxva = l16 * 64 + ((((koff >> 2)     + quad)) ^ ((l16 & 7) * 2)) * 4;
    const int oxvb = l16 * 64 + ((((koff >> 2) + 4 + quad)) ^ ((l16 & 7) * 2)) * 4;

    float m_ = -1e30f, l_ = 0.f;
    float4e oa[4];
    #pragma unroll
    for (int n = 0; n < 4; ++n) oa[n] = (float4e){0.f, 0.f, 0.f, 0.f};

    // prologue: stage tile 0 into buf 0
    async_cp16(srcK, dstK0);
    async_cp16(srcV, dstV0);
    __syncthreads();                  // implicit vmcnt(0) drain

    #pragma unroll 2
    for (int k0 = 0; k0 < S; k0 += 64) {
        const int cur = (k0 >> 6) & 1;
        if (k0 + 64 < S) {            // issue next-tile DMA before compute
            async_cp16(srcK + (size_t)(k0 + 64) * D, cur ? dstK0 : dstK1);
            async_cp16(srcV + (k0 + 64),             cur ? dstV0 : dstV1);
        }
        const ushort* ksb = cur ? &U.s.Ks [1][0][0] : &U.s.Ks [0][0][0];
        const ushort* vsb = cur ? &U.s.Vts[1][0][0] : &U.s.Vts[0][0][0];

        // ---- scores for this wave's 32 keys: S^T[key][query] ----
        float4e sa[2];
        __builtin_amdgcn_s_setprio(1);
        #pragma unroll
        for (int kb = 0; kb < 2; ++kb) {
            const short8 xk0 = *(const short8*)&ksb[oxk[kb][0]];
            const short8 xk1 = *(const short8*)&ksb[oxk[kb][1]];
            float4e z = (float4e){0.f, 0.f, 0.f, 0.f};
            z      = __builtin_amdgcn_mfma_f32_16x16x32_bf16(xk0, yq0, z, 0, 0, 0);
            sa[kb] = __builtin_amdgcn_mfma_f32_16x16x32_bf16(xk1, yq1, z, 0, 0, 0);
        }
        __builtin_amdgcn_s_setprio(0);

        // ---- private online softmax: 8 in-lane + xor 16,32 ----
        float mx = -1e30f;
        #pragma unroll
        for (int kb = 0; kb < 2; ++kb)
            #pragma unroll
            for (int r = 0; r < 4; ++r) mx = fmaxf(mx, sa[kb][r]);
        mx = fmaxf(mx, __shfl_xor(mx, 16, 64));
        mx = fmaxf(mx, __shfl_xor(mx, 32, 64));

        // defer-max (T13): only rescale when tile max outgrows m_ by >8.
        // first iter: m_ = -1e30 -> full path, alpha = 0 zeroes l_/oa.
        const bool full = !__all(mx - m_ <= 8.f);
        if (full) {
            const float mn = fmaxf(m_, mx);
            const float alpha = __expf(m_ - mn);
            l_ *= alpha;
            m_ = mn;
            #pragma unroll
            for (int n = 0; n < 4; ++n)
                #pragma unroll
                for (int r = 0; r < 4; ++r) oa[n][r] *= alpha;
        }

        float p[2][4], ps = 0.f;
        #pragma unroll
        for (int kb = 0; kb < 2; ++kb)
            #pragma unroll
            for (int r = 0; r < 4; ++r) {
                p[kb][r] = __expf(sa[kb][r] - m_);   // bounded by e^8
                ps += p[kb][r];
            }

        // ---- PV B-operand = own p[] packed (slots j<4: kb0, j>=4: kb1) ----
        union { unsigned u[4]; short8 s8; } pa;
        pa.u[0] = pk2bf(p[0][0], p[0][1]);
        pa.u[1] = pk2bf(p[0][2], p[0][3]);
        pa.u[2] = pk2bf(p[1][0], p[1][1]);
        pa.u[3] = pk2bf(p[1][2], p[1][3]);

        ps += __shfl_xor(ps, 16, 64);
        ps += __shfl_xor(ps, 32, 64);
        l_ += ps;

        // ---- PV: A = V^T with the same slot permutation (2 x 8B per db) ----
        __builtin_amdgcn_s_setprio(1);
        #pragma unroll
        for (int db = 0; db < 4; ++db) {
            union { uint2 v2[2]; short8 s8; } xv;
            xv.v2[0] = *(const uint2*)&vsb[oxva + db * 1024];
            xv.v2[1] = *(const uint2*)&vsb[oxvb + db * 1024];
            oa[db] = __builtin_amdgcn_mfma_f32_16x16x32_bf16(xv.s8, pa.s8, oa[db], 0, 0, 0);
        }
        __builtin_amdgcn_s_setprio(0);

        __syncthreads();  // implicit vmcnt(0): tile t+1 staged; buf reads done
    }

    // ---- intra-block split-K combine (stage buffers dead; union reuse) ----
    if (w >= 4) {
        if (quad == 0) { U.c.Msc[wq][l16] = m_; U.c.Lsc[wq][l16] = l_; }
        #pragma unroll
        for (int db = 0; db < 4; ++db)
            *(float4*)&U.c.Osc[wq][l16][db * 16 + quad * 4] =
                *(const float4*)&oa[db];
    }
    __syncthreads();
    if (w < 4) {
        const float m1 = U.c.Msc[wq][l16], l1 = U.c.Lsc[wq][l16];
        const float mm = fmaxf(m_, m1);
        const float a0 = __expf(m_ - mm), a1 = __expf(m1 - mm);
        const float inv = 1.0f / (l_ * a0 + l1 * a1);
        const size_t crow = (size_t)(b * S + q0 + wq * 16 + l16) * D + hc;
        #pragma unroll
        for (int db = 0; db < 4; ++db) {
            const float4 o1 = *(const float4*)&U.c.Osc[wq][l16][db * 16 + quad * 4];
            uint2 ov;
            ov.x = pk2bf((oa[db][0] * a0 + o1.x * a1) * inv,
                         (oa[db][1] * a0 + o1.y * a1) * inv);
            ov.y = pk2bf((oa[db][2] * a0 + o1.z * a1) * inv,
                         (oa[db][3] * a0 + o1.w * a1) * inv);
            *(uint2*)&Ctx[crow + db * 16 + quad * 4] = ov;
        }
    }
}

// ===========================================================================
// Launch
// ===========================================================================
extern "C" void kernel_launch(void* const* d_in, const int* in_sizes, int n_in,
                              void* d_out, int out_size, void* d_ws, size_t ws_size,
                              hipStream_t stream)
{
    const float* x  = (const float*)d_in[0];
    const float* Wq = (const float*)d_in[1];
    const float* bq = (const float*)d_in[2];
    const float* Wk = (const float*)d_in[3];
    const float* bk = (const float*)d_in[4];
    const float* Wv = (const float*)d_in[5];
    const float* bv = (const float*)d_in[6];
    const float* Wo = (const float*)d_in[7];
    const float* bo = (const float*)d_in[8];

    const int M = 4096, D = 768;
    const size_t XE = (size_t)M * D;     // 3,145,728
    const size_t WE = (size_t)D * D;     //   589,824

    ushort* xb   = (ushort*)d_ws;
    ushort* wtq  = xb   + XE;            // wtq/wtk/wtv/wto contiguous
    ushort* wto  = wtq  + 3 * WE;
    ushort* qb   = wto  + WE;            // qb/kb/vb contiguous
    ushort* kb   = qb   + XE;
    ushort* vb   = kb   + XE;
    ushort* ctxb = vb   + XE;
    ushort* vt   = xb;                   // reuse xb (dead after fused GEMM)

    cast_f32_bf16<<<(int)(XE / 4 / 256), 256, 0, stream>>>(x, xb, (int)(XE / 4));

    transpose_cast_w4<<<dim3(12, 12, 4), 256, 0, stream>>>(Wq, Wk, Wv, Wo, wtq);

    gemm_qkv_fused<<<dim3(2304 / 128, 4096 / 128), 256, 0, stream>>>(
        xb, wtq, bq, bk, bv, qb);

    transpose_v<<<dim3(32, 12, 2), 256, 0, stream>>>(vb, vt);

    attn_mfma<<<dim3(2048 / 64, 12, 2), 512, 0, stream>>>(qb, kb, vt, ctxb);

    gemm_wo_128<<<dim3(768 / 128, 4096 / 128), 256, 0, stream>>>(
        ctxb, wto, bo, (float*)d_out);
}

// Round 5
// 183.052 us; speedup vs baseline: 1.0471x; 1.0471x over previous
//
#include <hip/hip_runtime.h>
#include <hip/hip_bf16.h>

// ---------------------------------------------------------------------------
// B=2, S=2048, D=768, H=12, Dh=64. M = B*S = 4096.
// R19: attn rewritten on 32x32 MFMA with ZERO-SHUFFLE PV (no permlane, no
// P-LDS): slot->key bijection sigma_m(hi*8+j') = 4hi+(j'&3)+8*(j'>>2)+16m
// applied to BOTH PV operands => B-operand = lane's own p[8m..8m+7] packed
// (r = j'+8m from the verified C-layout kk(r)=(r&3)+8*(r>>2)+4hi).
//  - 8 waves = 2 qg x 4 ks; KVBLK=128, QBLK=64. Per wave per tile:
//    4 score MFMA (d-chain) + 4 PV MFMA, 1 barrier.
//  - K [128][64] ^(row&7) 16B-granule swizzle (R15-proven, conflict-free
//    b128); V [64][128] ^(d&7) 16B-granule swizzle (PV b64 reads hit the
//    32-bank 4/bank minimum -- verified by bank arithmetic).
//  - reduces via __shfl_xor(.,32) only (proven primitive).
//  - defer-max (T13, THR=8); LDS 64KB union'd with 4-way split-K combine.
// Non-attn parts = R15/R18 verbatim.
// ---------------------------------------------------------------------------

typedef __attribute__((ext_vector_type(8))) short short8;   // 8 x bf16 (4 VGPR)
typedef __attribute__((ext_vector_type(4))) float float4e;  // 4 x fp32 acc
typedef __attribute__((ext_vector_type(16))) float f32x16;  // 32x32 acc

__device__ __forceinline__ ushort f2bf(float f) {
    union { float f; unsigned u; } v; v.f = f;
    unsigned r = v.u + 0x7FFF + ((v.u >> 16) & 1);
    return (ushort)(r >> 16);
}

// packed RNE fp32x2 -> bf16x2 (v_cvt_pk_bf16_f32); low 16 bits = first arg
__device__ __forceinline__ unsigned pk2bf(float a, float b) {
    float2 t; t.x = a; t.y = b;
    __hip_bfloat162 h = __float22bfloat162_rn(t);
    union { __hip_bfloat162 h; unsigned u; } cv; cv.h = h;
    return cv.u;
}

// async 16B global -> LDS; LDS dest = wave-uniform base + lane*16.
__device__ __forceinline__ void async_cp16(const ushort* g, ushort* l) {
    __builtin_amdgcn_global_load_lds(
        (const __attribute__((address_space(1))) unsigned int*)g,
        (__attribute__((address_space(3))) unsigned int*)l,
        16, 0, 0);
}

// ===========================================================================
// x [4096x768] fp32 -> bf16
// ===========================================================================
__global__ __launch_bounds__(256) void cast_f32_bf16(
    const float* __restrict__ in, ushort* __restrict__ out, int n4)
{
    int i = blockIdx.x * blockDim.x + threadIdx.x;
    if (i < n4) {
        float4 v = *(const float4*)&in[(size_t)i * 4];
        ushort4 o;
        o.x = f2bf(v.x); o.y = f2bf(v.y); o.z = f2bf(v.z); o.w = f2bf(v.w);
        *(ushort4*)&out[(size_t)i * 4] = o;
    }
}

// ===========================================================================
// All 4 weight transposes in one launch: z selects Wq/Wk/Wv/Wo.
// ===========================================================================
__global__ __launch_bounds__(256) void transpose_cast_w4(
    const float* __restrict__ W0, const float* __restrict__ W1,
    const float* __restrict__ W2, const float* __restrict__ W3,
    ushort* __restrict__ WtBase)
{
    __shared__ float t[64][65];
    const int z = blockIdx.z;
    const float* W = (z == 0) ? W0 : (z == 1) ? W1 : (z == 2) ? W2 : W3;
    ushort* Wt = WtBase + (size_t)z * (768u * 768u);

    const int tid = threadIdx.x;
    const int c  = tid & 63;
    const int rg = tid >> 6;
    const int k0 = blockIdx.y * 64, n0 = blockIdx.x * 64;
    #pragma unroll
    for (int r = 0; r < 16; ++r) {
        const int row = rg * 16 + r;
        t[row][c] = W[(size_t)(k0 + row) * 768 + n0 + c];
    }
    __syncthreads();
    #pragma unroll
    for (int r = 0; r < 16; ++r) {
        const int row = rg * 16 + r;
        Wt[(size_t)(n0 + row) * 768 + k0 + c] = f2bf(t[c][row]);
    }
}

// ===========================================================================
// V [4096x768] bf16 -> VT[b][h][d][s] bf16 (s-major per head).
// ===========================================================================
__global__ __launch_bounds__(256) void transpose_v(
    const ushort* __restrict__ Vb, ushort* __restrict__ VT)
{
    __shared__ ushort t[64][72];
    const int tid = threadIdx.x;
    const int b = blockIdx.z, h = blockIdx.y, s0 = blockIdx.x * 64;
    const int lr = tid >> 3;          // 0..31
    const int lc = (tid & 7) * 8;     // 0..56

    #pragma unroll
    for (int half = 0; half < 64; half += 32) {
        const int row = lr + half;
        *(uint4*)&t[row][lc] =
            *(const uint4*)&Vb[(size_t)(b * 2048 + s0 + row) * 768 + h * 64 + lc];
    }
    __syncthreads();
    #pragma unroll
    for (int half = 0; half < 64; half += 32) {
        const int d = lr + half;
        ushort tmp[8];
        #pragma unroll
        for (int i = 0; i < 8; ++i) tmp[i] = t[lc + i][d];
        *(uint4*)&VT[((size_t)(b * 12 + h) * 64 + d) * 2048 + s0 + lc] =
            *(const uint4*)tmp;
    }
}

// ===========================================================================
// Fused QKV GEMM: Out[M,2304] = x[M,768] @ [Wq|Wk|Wv]^T + [bq|bk|bv]
// 128x128 tile, BK=32, 4 waves 2x2, 16 accs/wave; m97-style async staging.
// ===========================================================================
__global__ __launch_bounds__(256) void gemm_qkv_fused(
    const ushort* __restrict__ A, const ushort* __restrict__ Bt,
    const float* __restrict__ bq, const float* __restrict__ bk,
    const float* __restrict__ bv, ushort* __restrict__ Outbase)
{
    constexpr int K = 768;
    __shared__ ushort As[128][32];   // unpadded: required by global_load_lds
    __shared__ ushort Bs[128][32];

    const int tid  = threadIdx.x;
    const int w    = tid >> 6;
    const int lane = tid & 63;
    const int l16  = lane & 15;
    const int quad = lane >> 4;
    const int wr   = (w >> 1) * 64;
    const int wc   = (w & 1) * 64;
    const int row0 = blockIdx.y * 128, col0 = blockIdx.x * 128;

    const int r4 = lane >> 2;
    const int c8 = (lane & 3) * 8;

    float4e acc[4][4];
    #pragma unroll
    for (int mi = 0; mi < 4; ++mi)
        #pragma unroll
        for (int ni = 0; ni < 4; ++ni) acc[mi][ni] = (float4e){0.f,0.f,0.f,0.f};

    for (int k0 = 0; k0 < K; k0 += 32) {
        #pragma unroll
        for (int i = 0; i < 2; ++i) {
            const int rr = w * 32 + i * 16;
            async_cp16(&A [(size_t)(row0 + rr + r4) * K + k0 + c8], &As[rr][0]);
            async_cp16(&Bt[(size_t)(col0 + rr + r4) * K + k0 + c8], &Bs[rr][0]);
        }
        __syncthreads();   // drains vmcnt -> staged data visible

        short8 af[4], bf[4];
        #pragma unroll
        for (int i = 0; i < 4; ++i) {
            af[i] = *(const short8*)&As[wr + i * 16 + l16][quad * 8];
            bf[i] = *(const short8*)&Bs[wc + i * 16 + l16][quad * 8];
        }
        #pragma unroll
        for (int mi = 0; mi < 4; ++mi)
            #pragma unroll
            for (int ni = 0; ni < 4; ++ni)
                acc[mi][ni] = __builtin_amdgcn_mfma_f32_16x16x32_bf16(
                    af[mi], bf[ni], acc[mi][ni], 0, 0, 0);
        __syncthreads();
    }

    const int seg = (col0 >= 1536) ? 2 : (col0 >= 768 ? 1 : 0);
    const float* bias = (seg == 0) ? bq : (seg == 1) ? bk : bv;
    const int ncol0 = col0 - seg * 768 + wc;
    ushort* outp = Outbase + (size_t)seg * (4096u * 768u);

    #pragma unroll
    for (int ni = 0; ni < 4; ++ni) {
        const int col = ncol0 + ni * 16 + l16;
        const float bs = bias[col];
        #pragma unroll
        for (int mi = 0; mi < 4; ++mi) {
            #pragma unroll
            for (int r = 0; r < 4; ++r) {
                const int row = row0 + wr + mi * 16 + quad * 4 + r;
                outp[(size_t)row * 768 + col] = f2bf(acc[mi][ni][r] + bs);
            }
        }
    }
}

// ===========================================================================
// Wo GEMM: C[4096,768](fp32) = ctx[4096,768] @ Wo^T + bo. 128x128 tile,
// register-prefetch staging.
// ===========================================================================
__global__ __launch_bounds__(256) void gemm_wo_128(
    const ushort* __restrict__ A, const ushort* __restrict__ Bt,
    const float* __restrict__ bias, float* __restrict__ Cout)
{
    constexpr int K = 768, N = 768;
    __shared__ ushort As[128][40];
    __shared__ ushort Bs[128][40];

    const int tid  = threadIdx.x;
    const int w    = tid >> 6;
    const int lane = tid & 63;
    const int l16  = lane & 15;
    const int quad = lane >> 4;
    const int wr   = (w >> 1) * 64;
    const int wc   = (w & 1) * 64;
    const int row0 = blockIdx.y * 128, col0 = blockIdx.x * 128;
    const int sr = tid >> 2, sc = (tid & 3) * 8;

    float4e acc[4][4];
    #pragma unroll
    for (int mi = 0; mi < 4; ++mi)
        #pragma unroll
        for (int ni = 0; ni < 4; ++ni) acc[mi][ni] = (float4e){0.f,0.f,0.f,0.f};

    uint4 a0 = *(const uint4*)&A [(size_t)(row0 + sr     ) * K + sc];
    uint4 a1 = *(const uint4*)&A [(size_t)(row0 + sr + 64) * K + sc];
    uint4 b0 = *(const uint4*)&Bt[(size_t)(col0 + sr     ) * K + sc];
    uint4 b1 = *(const uint4*)&Bt[(size_t)(col0 + sr + 64) * K + sc];

    for (int k0 = 0; k0 < K; k0 += 32) {
        *(uint4*)&As[sr     ][sc] = a0;
        *(uint4*)&As[sr + 64][sc] = a1;
        *(uint4*)&Bs[sr     ][sc] = b0;
        *(uint4*)&Bs[sr + 64][sc] = b1;
        __syncthreads();

        if (k0 + 32 < K) {
            const int kn = k0 + 32;
            a0 = *(const uint4*)&A [(size_t)(row0 + sr     ) * K + kn + sc];
            a1 = *(const uint4*)&A [(size_t)(row0 + sr + 64) * K + kn + sc];
            b0 = *(const uint4*)&Bt[(size_t)(col0 + sr     ) * K + kn + sc];
            b1 = *(const uint4*)&Bt[(size_t)(col0 + sr + 64) * K + kn + sc];
        }

        short8 af[4], bf[4];
        #pragma unroll
        for (int i = 0; i < 4; ++i) {
            af[i] = *(const short8*)&As[wr + i * 16 + l16][quad * 8];
            bf[i] = *(const short8*)&Bs[wc + i * 16 + l16][quad * 8];
        }
        #pragma unroll
        for (int mi = 0; mi < 4; ++mi)
            #pragma unroll
            for (int ni = 0; ni < 4; ++ni)
                acc[mi][ni] = __builtin_amdgcn_mfma_f32_16x16x32_bf16(
                    af[mi], bf[ni], acc[mi][ni], 0, 0, 0);
        __syncthreads();
    }

    #pragma unroll
    for (int ni = 0; ni < 4; ++ni) {
        const int col = col0 + wc + ni * 16 + l16;
        const float bs = bias[col];
        #pragma unroll
        for (int mi = 0; mi < 4; ++mi) {
            #pragma unroll
            for (int r = 0; r < 4; ++r) {
                const int row = row0 + wr + mi * 16 + quad * 4 + r;
                Cout[(size_t)row * N + col] = acc[mi][ni][r] + bs;
            }
        }
    }
}

// ===========================================================================
// Flash attention, 32x32 MFMA, zero-shuffle softmax+PV. 512 thr = 8 waves.
// Wave w: qg = w&1 (32 queries), ks = w>>1 (32-key slice of 128-key tile).
// C-layout (HW-verified): col=l&31, row=(r&3)+8*(r>>2)+4*(l>>5).
// Scores: sa[r] = S^T[key=ks*32+kk(r)][q], kk(r)=(r&3)+8*(r>>2)+4*hi.
// PV slot bijection sigma_m(hi*8+j') = 4hi+(j'&3)+8*(j'>>2)+16m
//   => B-operand = own p[8m..8m+7]; A-operand = V^T[d][ks*32+sigma_m(.)]
//   = two 8B halves of 16B granules (ks*4+2m, ks*4+2m+1) at half hi.
// Swizzles (both-sides, rule 21): K granule ^(row&7); V granule ^(d&7).
// Pipeline: stage t+1 (4 DMA) -> compute t -> 1 barrier. 16 tiles.
// Epilogue: 4-way split-K combine in LDS (union with stage buffers).
// ===========================================================================
__global__ __launch_bounds__(512, 4) void attn_mfma(
    const ushort* __restrict__ Qg, const ushort* __restrict__ Kgl,
    const ushort* __restrict__ VT, ushort* __restrict__ Ctx)
{
    constexpr int S = 2048, D = 768;
    __shared__ union {
        struct {                      // main-loop stage buffers (swizzled)
            ushort Ks [2][128][64];   // [buf][key][16B-gran ^ (key&7)]
            ushort Vts[2][64][128];   // [buf][d][16B-gran ^ (d&7)]
        } s;
        struct {                      // epilogue split-K combine buffers
            float Osc[6][2048];       // [slot][lane*32 + (g^(lane&7))*4 + e]
            float Msc[6][32];
            float Lsc[6][32];
        } c;
    } U;

    const int tid  = threadIdx.x;
    const int w    = tid >> 6;        // 0..7
    const int qg   = w & 1;           // query group (32 q)
    const int ks   = w >> 1;          // key slice 0..3 (32 of 128)
    const int lane = tid & 63;
    const int l31  = lane & 31;
    const int hi   = lane >> 5;
    const int b = blockIdx.z, h = blockIdx.y, q0 = blockIdx.x * 64;
    const size_t hc = (size_t)h * 64;

    // Q fragments (B-operand): yq[dc][j'] = Q[q][dc*16 + hi*8 + j']
    const size_t qrow = (size_t)(b * S + q0 + qg * 32 + l31) * D + hc + hi * 8;
    short8 yq[4];
    #pragma unroll
    for (int dc = 0; dc < 4; ++dc) yq[dc] = *(const short8*)&Qg[qrow + dc * 16];

    // ---- staging (rule 21: pre-swizzled global source, linear LDS dest) ----
    const int sr  = tid >> 3;                    // K row 0..63 (+64 2nd issue)
    const int kgr = (tid & 7) ^ (sr & 7);        // 16B granule of 8
    const ushort* srcK = &Kgl[(size_t)(b * S + sr) * D + hc + kgr * 8];
    const int vr  = tid >> 4;                    // V row 0..31 (+32 2nd issue)
    const int vgr = (tid & 15) ^ (vr & 7);       // 16B granule of 16
    const ushort* srcV = &VT[((size_t)(b * 12 + h) * 64 + vr) * 2048 + vgr * 8];
    ushort* dK0 = &U.s.Ks [0][w * 8][0];         // wave-uniform bases
    ushort* dK1 = &U.s.Ks [1][w * 8][0];
    ushort* dV0 = &U.s.Vts[0][w * 4][0];
    ushort* dV1 = &U.s.Vts[1][w * 4][0];

    // ---- loop-invariant swizzled read offsets (ushort units) ----
    int okf[4];                                  // K b128: row ks*32+l31
    #pragma unroll
    for (int dc = 0; dc < 4; ++dc)
        okf[dc] = (ks * 32 + l31) * 64 + ((dc * 2 + hi) ^ (l31 & 7)) * 8;
    int ovo[2][2][2];                            // V b64: [a][m][chunk]
    #pragma unroll
    for (int a = 0; a < 2; ++a)
        #pragma unroll
        for (int m = 0; m < 2; ++m)
            #pragma unroll
            for (int c2 = 0; c2 < 2; ++c2)
                ovo[a][m][c2] = (a * 32 + l31) * 128 +
                    ((ks * 4 + m * 2 + c2) ^ (l31 & 7)) * 8 + hi * 4;

    float m_ = -1e30f, l_ = 0.f;
    f32x16 oa0, oa1;
    #pragma unroll
    for (int i = 0; i < 16; ++i) { oa0[i] = 0.f; oa1[i] = 0.f; }

    // prologue: stage tile 0 into buf 0
    async_cp16(srcK,                  dK0);
    async_cp16(srcK + (size_t)64 * D, dK0 + 64 * 64);
    async_cp16(srcV,                  dV0);
    async_cp16(srcV + 32 * 2048,      dV0 + 32 * 128);
    __syncthreads();                  // implicit vmcnt(0) drain

    #pragma unroll 2
    for (int t = 0; t < 16; ++t) {
        const int cur = t & 1;
        const ushort* ksb = cur ? &U.s.Ks [1][0][0] : &U.s.Ks [0][0][0];
        const ushort* vsb = cur ? &U.s.Vts[1][0][0] : &U.s.Vts[0][0][0];
        if (t + 1 < 16) {             // issue next-tile DMA before compute
            const size_t kn = (size_t)(t + 1) * 128;
            ushort* dK = cur ? dK0 : dK1;
            ushort* dV = cur ? dV0 : dV1;
            async_cp16(srcK + kn * D,              dK);
            async_cp16(srcK + (kn + 64) * D,       dK + 64 * 64);
            async_cp16(srcV + kn,                  dV);
            async_cp16(srcV + kn + 32 * 2048,      dV + 32 * 128);
        }

        // ---- scores: S^T[32k x 32q], d-chain of 4 MFMAs ----
        f32x16 sa;
        #pragma unroll
        for (int i = 0; i < 16; ++i) sa[i] = 0.f;
        __builtin_amdgcn_s_setprio(1);
        #pragma unroll
        for (int dc = 0; dc < 4; ++dc) {
            const short8 xk = *(const short8*)&ksb[okf[dc]];
            sa = __builtin_amdgcn_mfma_f32_32x32x16_bf16(xk, yq[dc], sa, 0, 0, 0);
        }
        __builtin_amdgcn_s_setprio(0);

        // ---- online softmax: 15 in-lane fmax + 1 shfl32 ----
        float mx = sa[0];
        #pragma unroll
        for (int r = 1; r < 16; ++r) mx = fmaxf(mx, sa[r]);
        mx = fmaxf(mx, __shfl_xor(mx, 32, 64));

        // defer-max (T13): rescale only when tile max outgrows m_ by >8.
        const bool full = !__all(mx - m_ <= 8.f);
        if (full) {
            const float mn = fmaxf(m_, mx);
            const float alpha = __expf(m_ - mn);   // first iter: 0
            l_ *= alpha;
            m_ = mn;
            #pragma unroll
            for (int i = 0; i < 16; ++i) { oa0[i] *= alpha; oa1[i] *= alpha; }
        }

        float p[16], ps = 0.f;
        #pragma unroll
        for (int r = 0; r < 16; ++r) {
            p[r] = __expf(sa[r] - m_);             // bounded by e^8
            ps += p[r];
        }
        ps += __shfl_xor(ps, 32, 64);
        l_ += ps;

        // ---- PV B-operands: own p[] packed (slot j' = p[8m + j']) ----
        union { unsigned u[4]; short8 s8; } pa0, pa1;
        pa0.u[0] = pk2bf(p[0],  p[1]);  pa0.u[1] = pk2bf(p[2],  p[3]);
        pa0.u[2] = pk2bf(p[4],  p[5]);  pa0.u[3] = pk2bf(p[6],  p[7]);
        pa1.u[0] = pk2bf(p[8],  p[9]);  pa1.u[1] = pk2bf(p[10], p[11]);
        pa1.u[2] = pk2bf(p[12], p[13]); pa1.u[3] = pk2bf(p[14], p[15]);

        // ---- PV: O^T[64d x 32q] += V^T x P (4 MFMAs, 8 b64 V-reads) ----
        __builtin_amdgcn_s_setprio(1);
        {
            union { uint2 v2[2]; short8 s8; } xv;
            xv.v2[0] = *(const uint2*)&vsb[ovo[0][0][0]];
            xv.v2[1] = *(const uint2*)&vsb[ovo[0][0][1]];
            oa0 = __builtin_amdgcn_mfma_f32_32x32x16_bf16(xv.s8, pa0.s8, oa0, 0, 0, 0);
            xv.v2[0] = *(const uint2*)&vsb[ovo[0][1][0]];
            xv.v2[1] = *(const uint2*)&vsb[ovo[0][1][1]];
            oa0 = __builtin_amdgcn_mfma_f32_32x32x16_bf16(xv.s8, pa1.s8, oa0, 0, 0, 0);
            xv.v2[0] = *(const uint2*)&vsb[ovo[1][0][0]];
            xv.v2[1] = *(const uint2*)&vsb[ovo[1][0][1]];
            oa1 = __builtin_amdgcn_mfma_f32_32x32x16_bf16(xv.s8, pa0.s8, oa1, 0, 0, 0);
            xv.v2[0] = *(const uint2*)&vsb[ovo[1][1][0]];
            xv.v2[1] = *(const uint2*)&vsb[ovo[1][1][1]];
            oa1 = __builtin_amdgcn_mfma_f32_32x32x16_bf16(xv.s8, pa1.s8, oa1, 0, 0, 0);
        }
        __builtin_amdgcn_s_setprio(0);

        __syncthreads();  // implicit vmcnt(0): tile t+1 staged; buf reads done
    }

    // ---- 4-way split-K combine (stage buffers dead; union reuse) ----
    if (ks > 0) {
        const int slot = (ks - 1) * 2 + qg;
        float* ob = &U.c.Osc[slot][lane * 32];
        #pragma unroll
        for (int g = 0; g < 4; ++g) {
            float4 v0, v1;
            v0.x = oa0[g * 4 + 0]; v0.y = oa0[g * 4 + 1];
            v0.z = oa0[g * 4 + 2]; v0.w = oa0[g * 4 + 3];
            v1.x = oa1[g * 4 + 0]; v1.y = oa1[g * 4 + 1];
            v1.z = oa1[g * 4 + 2]; v1.w = oa1[g * 4 + 3];
            *(float4*)&ob[(( g     ) ^ (lane & 7)) * 4] = v0;
            *(float4*)&ob[(((g + 4)) ^ (lane & 7)) * 4] = v1;
        }
        if (hi == 0) {
            U.c.Msc[slot][l31] = m_;
            U.c.Lsc[slot][l31] = l_;
        }
    }
    __syncthreads();
    if (ks == 0) {
        const float m1 = U.c.Msc[qg][l31];
        const float m2 = U.c.Msc[2 + qg][l31];
        const float m3 = U.c.Msc[4 + qg][l31];
        const float M  = fmaxf(fmaxf(m_, m1), fmaxf(m2, m3));
        const float a0 = __expf(m_ - M), a1 = __expf(m1 - M),
                    a2 = __expf(m2 - M), a3 = __expf(m3 - M);
        const float l1 = U.c.Lsc[qg][l31];
        const float l2 = U.c.Lsc[2 + qg][l31];
        const float l3 = U.c.Lsc[4 + qg][l31];
        const float inv = 1.0f / (l_ * a0 + l1 * a1 + l2 * a2 + l3 * a3);

        float o[32];
        #pragma unroll
        for (int i = 0; i < 16; ++i) { o[i] = oa0[i] * a0; o[16 + i] = oa1[i] * a0; }
        #pragma unroll
        for (int s = 0; s < 3; ++s) {
            const float as = (s == 0) ? a1 : (s == 1) ? a2 : a3;
            const float* ob = &U.c.Osc[s * 2 + qg][lane * 32];
            #pragma unroll
            for (int gg = 0; gg < 8; ++gg) {
                const float4 v = *(const float4*)&ob[(gg ^ (lane & 7)) * 4];
                o[gg * 4 + 0] += v.x * as;
                o[gg * 4 + 1] += v.y * as;
                o[gg * 4 + 2] += v.z * as;
                o[gg * 4 + 3] += v.w * as;
            }
        }

        // lane owns q = q0+qg*32+l31; d = a*32 + 8*rq + 4*hi + e
        const size_t crow = (size_t)(b * S + q0 + qg * 32 + l31) * D + hc;
        #pragma unroll
        for (int a = 0; a < 2; ++a)
            #pragma unroll
            for (int rq = 0; rq < 4; ++rq) {
                const int base = a * 16 + rq * 4;
                uint2 ov;
                ov.x = pk2bf(o[base + 0] * inv, o[base + 1] * inv);
                ov.y = pk2bf(o[base + 2] * inv, o[base + 3] * inv);
                *(uint2*)&Ctx[crow + a * 32 + rq * 8 + hi * 4] = ov;
            }
    }
}

// ===========================================================================
// Launch
// ===========================================================================
extern "C" void kernel_launch(void* const* d_in, const int* in_sizes, int n_in,
                              void* d_out, int out_size, void* d_ws, size_t ws_size,
                              hipStream_t stream)
{
    const float* x  = (const float*)d_in[0];
    const float* Wq = (const float*)d_in[1];
    const float* bq = (const float*)d_in[2];
    const float* Wk = (const float*)d_in[3];
    const float* bk = (const float*)d_in[4];
    const float* Wv = (const float*)d_in[5];
    const float* bv = (const float*)d_in[6];
    const float* Wo = (const float*)d_in[7];
    const float* bo = (const float*)d_in[8];

    const int M = 4096, D = 768;
    const size_t XE = (size_t)M * D;     // 3,145,728
    const size_t WE = (size_t)D * D;     //   589,824

    ushort* xb   = (ushort*)d_ws;
    ushort* wtq  = xb   + XE;            // wtq/wtk/wtv/wto contiguous
    ushort* wto  = wtq  + 3 * WE;
    ushort* qb   = wto  + WE;            // qb/kb/vb contiguous
    ushort* kb   = qb   + XE;
    ushort* vb   = kb   + XE;
    ushort* ctxb = vb   + XE;
    ushort* vt   = xb;                   // reuse xb (dead after fused GEMM)

    cast_f32_bf16<<<(int)(XE / 4 / 256), 256, 0, stream>>>(x, xb, (int)(XE / 4));

    transpose_cast_w4<<<dim3(12, 12, 4), 256, 0, stream>>>(Wq, Wk, Wv, Wo, wtq);

    gemm_qkv_fused<<<dim3(2304 / 128, 4096 / 128), 256, 0, stream>>>(
        xb, wtq, bq, bk, bv, qb);

    transpose_v<<<dim3(32, 12, 2), 256, 0, stream>>>(vb, vt);

    attn_mfma<<<dim3(2048 / 64, 12, 2), 512, 0, stream>>>(qb, kb, vt, ctxb);

    gemm_wo_128<<<dim3(768 / 128, 4096 / 128), 256, 0, stream>>>(
        ctxb, wto, bo, (float*)d_out);
}

// Round 6
// 182.362 us; speedup vs baseline: 1.0511x; 1.0038x over previous
//
#include <hip/hip_runtime.h>
#include <hip/hip_bf16.h>

// ---------------------------------------------------------------------------
// B=2, S=2048, D=768, H=12, Dh=64. M = B*S = 4096.
// R20: attn = R19 verbatim (passed, 59.5us: 32x32 MFMA, zero-shuffle PV).
// Both GEMMs ported to the session-proven 2-phase async pipeline:
//   double-buffered global_load_lds staging, issue DMA for K-step t+1 into
//   buf^1 BEFORE computing step t from buf, ONE __syncthreads per step
//   (implicit vmcnt(0)+lgkm drain = pipeline wait). Barriers 48->24.
//   gemm_wo additionally moves from register-staged ds_writes to DMA
//   staging (identical addressing to the proven qkv pattern).
// ---------------------------------------------------------------------------

typedef __attribute__((ext_vector_type(8))) short short8;   // 8 x bf16 (4 VGPR)
typedef __attribute__((ext_vector_type(4))) float float4e;  // 4 x fp32 acc
typedef __attribute__((ext_vector_type(16))) float f32x16;  // 32x32 acc

__device__ __forceinline__ ushort f2bf(float f) {
    union { float f; unsigned u; } v; v.f = f;
    unsigned r = v.u + 0x7FFF + ((v.u >> 16) & 1);
    return (ushort)(r >> 16);
}

// packed RNE fp32x2 -> bf16x2 (v_cvt_pk_bf16_f32); low 16 bits = first arg
__device__ __forceinline__ unsigned pk2bf(float a, float b) {
    float2 t; t.x = a; t.y = b;
    __hip_bfloat162 h = __float22bfloat162_rn(t);
    union { __hip_bfloat162 h; unsigned u; } cv; cv.h = h;
    return cv.u;
}

// async 16B global -> LDS; LDS dest = wave-uniform base + lane*16.
__device__ __forceinline__ void async_cp16(const ushort* g, ushort* l) {
    __builtin_amdgcn_global_load_lds(
        (const __attribute__((address_space(1))) unsigned int*)g,
        (__attribute__((address_space(3))) unsigned int*)l,
        16, 0, 0);
}

// ===========================================================================
// x [4096x768] fp32 -> bf16
// ===========================================================================
__global__ __launch_bounds__(256) void cast_f32_bf16(
    const float* __restrict__ in, ushort* __restrict__ out, int n4)
{
    int i = blockIdx.x * blockDim.x + threadIdx.x;
    if (i < n4) {
        float4 v = *(const float4*)&in[(size_t)i * 4];
        ushort4 o;
        o.x = f2bf(v.x); o.y = f2bf(v.y); o.z = f2bf(v.z); o.w = f2bf(v.w);
        *(ushort4*)&out[(size_t)i * 4] = o;
    }
}

// ===========================================================================
// All 4 weight transposes in one launch: z selects Wq/Wk/Wv/Wo.
// ===========================================================================
__global__ __launch_bounds__(256) void transpose_cast_w4(
    const float* __restrict__ W0, const float* __restrict__ W1,
    const float* __restrict__ W2, const float* __restrict__ W3,
    ushort* __restrict__ WtBase)
{
    __shared__ float t[64][65];
    const int z = blockIdx.z;
    const float* W = (z == 0) ? W0 : (z == 1) ? W1 : (z == 2) ? W2 : W3;
    ushort* Wt = WtBase + (size_t)z * (768u * 768u);

    const int tid = threadIdx.x;
    const int c  = tid & 63;
    const int rg = tid >> 6;
    const int k0 = blockIdx.y * 64, n0 = blockIdx.x * 64;
    #pragma unroll
    for (int r = 0; r < 16; ++r) {
        const int row = rg * 16 + r;
        t[row][c] = W[(size_t)(k0 + row) * 768 + n0 + c];
    }
    __syncthreads();
    #pragma unroll
    for (int r = 0; r < 16; ++r) {
        const int row = rg * 16 + r;
        Wt[(size_t)(n0 + row) * 768 + k0 + c] = f2bf(t[c][row]);
    }
}

// ===========================================================================
// V [4096x768] bf16 -> VT[b][h][d][s] bf16 (s-major per head).
// ===========================================================================
__global__ __launch_bounds__(256) void transpose_v(
    const ushort* __restrict__ Vb, ushort* __restrict__ VT)
{
    __shared__ ushort t[64][72];
    const int tid = threadIdx.x;
    const int b = blockIdx.z, h = blockIdx.y, s0 = blockIdx.x * 64;
    const int lr = tid >> 3;          // 0..31
    const int lc = (tid & 7) * 8;     // 0..56

    #pragma unroll
    for (int half = 0; half < 64; half += 32) {
        const int row = lr + half;
        *(uint4*)&t[row][lc] =
            *(const uint4*)&Vb[(size_t)(b * 2048 + s0 + row) * 768 + h * 64 + lc];
    }
    __syncthreads();
    #pragma unroll
    for (int half = 0; half < 64; half += 32) {
        const int d = lr + half;
        ushort tmp[8];
        #pragma unroll
        for (int i = 0; i < 8; ++i) tmp[i] = t[lc + i][d];
        *(uint4*)&VT[((size_t)(b * 12 + h) * 64 + d) * 2048 + s0 + lc] =
            *(const uint4*)tmp;
    }
}

// ===========================================================================
// Fused QKV GEMM: Out[M,2304] = x[M,768] @ [Wq|Wk|Wv]^T + [bq|bk|bv]
// 128x128 tile, BK=32, 4 waves 2x2, 16 accs/wave.
// R20: 2-phase async pipeline -- double-buffered global_load_lds, issue
// DMA for step t+1 before computing step t, ONE barrier per step.
// ===========================================================================
__global__ __launch_bounds__(256) void gemm_qkv_fused(
    const ushort* __restrict__ A, const ushort* __restrict__ Bt,
    const float* __restrict__ bq, const float* __restrict__ bk,
    const float* __restrict__ bv, ushort* __restrict__ Outbase)
{
    constexpr int K = 768;
    __shared__ ushort As[2][128][32];   // unpadded: required by global_load_lds
    __shared__ ushort Bs[2][128][32];

    const int tid  = threadIdx.x;
    const int w    = tid >> 6;
    const int lane = tid & 63;
    const int l16  = lane & 15;
    const int quad = lane >> 4;
    const int wr   = (w >> 1) * 64;
    const int wc   = (w & 1) * 64;
    const int row0 = blockIdx.y * 128, col0 = blockIdx.x * 128;

    const int r4 = lane >> 2;
    const int c8 = (lane & 3) * 8;

    float4e acc[4][4];
    #pragma unroll
    for (int mi = 0; mi < 4; ++mi)
        #pragma unroll
        for (int ni = 0; ni < 4; ++ni) acc[mi][ni] = (float4e){0.f,0.f,0.f,0.f};

    // prologue: stage K-step 0 into buf 0
    #pragma unroll
    for (int i = 0; i < 2; ++i) {
        const int rr = w * 32 + i * 16;
        async_cp16(&A [(size_t)(row0 + rr + r4) * K + c8], &As[0][rr][0]);
        async_cp16(&Bt[(size_t)(col0 + rr + r4) * K + c8], &Bs[0][rr][0]);
    }
    __syncthreads();   // implicit vmcnt(0) drain

    for (int k0 = 0; k0 < K; k0 += 32) {
        const int cur = (k0 >> 5) & 1;
        if (k0 + 32 < K) {            // issue next-step DMA before compute
            #pragma unroll
            for (int i = 0; i < 2; ++i) {
                const int rr = w * 32 + i * 16;
                async_cp16(&A [(size_t)(row0 + rr + r4) * K + k0 + 32 + c8],
                           &As[cur ^ 1][rr][0]);
                async_cp16(&Bt[(size_t)(col0 + rr + r4) * K + k0 + 32 + c8],
                           &Bs[cur ^ 1][rr][0]);
            }
        }

        short8 af[4], bf[4];
        #pragma unroll
        for (int i = 0; i < 4; ++i) {
            af[i] = *(const short8*)&As[cur][wr + i * 16 + l16][quad * 8];
            bf[i] = *(const short8*)&Bs[cur][wc + i * 16 + l16][quad * 8];
        }
        #pragma unroll
        for (int mi = 0; mi < 4; ++mi)
            #pragma unroll
            for (int ni = 0; ni < 4; ++ni)
                acc[mi][ni] = __builtin_amdgcn_mfma_f32_16x16x32_bf16(
                    af[mi], bf[ni], acc[mi][ni], 0, 0, 0);
        __syncthreads();  // next-step staged + this step's reads drained
    }

    const int seg = (col0 >= 1536) ? 2 : (col0 >= 768 ? 1 : 0);
    const float* bias = (seg == 0) ? bq : (seg == 1) ? bk : bv;
    const int ncol0 = col0 - seg * 768 + wc;
    ushort* outp = Outbase + (size_t)seg * (4096u * 768u);

    #pragma unroll
    for (int ni = 0; ni < 4; ++ni) {
        const int col = ncol0 + ni * 16 + l16;
        const float bs = bias[col];
        #pragma unroll
        for (int mi = 0; mi < 4; ++mi) {
            #pragma unroll
            for (int r = 0; r < 4; ++r) {
                const int row = row0 + wr + mi * 16 + quad * 4 + r;
                outp[(size_t)row * 768 + col] = f2bf(acc[mi][ni][r] + bs);
            }
        }
    }
}

// ===========================================================================
// Wo GEMM: C[4096,768](fp32) = ctx[4096,768] @ Wo^T + bo. 128x128 tile.
// R20: same 2-phase async DMA pipeline as gemm_qkv (was register-staged
// ds_writes with 2 barriers/step).
// ===========================================================================
__global__ __launch_bounds__(256) void gemm_wo_128(
    const ushort* __restrict__ A, const ushort* __restrict__ Bt,
    const float* __restrict__ bias, float* __restrict__ Cout)
{
    constexpr int K = 768, N = 768;
    __shared__ ushort As[2][128][32];
    __shared__ ushort Bs[2][128][32];

    const int tid  = threadIdx.x;
    const int w    = tid >> 6;
    const int lane = tid & 63;
    const int l16  = lane & 15;
    const int quad = lane >> 4;
    const int wr   = (w >> 1) * 64;
    const int wc   = (w & 1) * 64;
    const int row0 = blockIdx.y * 128, col0 = blockIdx.x * 128;

    const int r4 = lane >> 2;
    const int c8 = (lane & 3) * 8;

    float4e acc[4][4];
    #pragma unroll
    for (int mi = 0; mi < 4; ++mi)
        #pragma unroll
        for (int ni = 0; ni < 4; ++ni) acc[mi][ni] = (float4e){0.f,0.f,0.f,0.f};

    // prologue: stage K-step 0 into buf 0
    #pragma unroll
    for (int i = 0; i < 2; ++i) {
        const int rr = w * 32 + i * 16;
        async_cp16(&A [(size_t)(row0 + rr + r4) * K + c8], &As[0][rr][0]);
        async_cp16(&Bt[(size_t)(col0 + rr + r4) * K + c8], &Bs[0][rr][0]);
    }
    __syncthreads();

    for (int k0 = 0; k0 < K; k0 += 32) {
        const int cur = (k0 >> 5) & 1;
        if (k0 + 32 < K) {
            #pragma unroll
            for (int i = 0; i < 2; ++i) {
                const int rr = w * 32 + i * 16;
                async_cp16(&A [(size_t)(row0 + rr + r4) * K + k0 + 32 + c8],
                           &As[cur ^ 1][rr][0]);
                async_cp16(&Bt[(size_t)(col0 + rr + r4) * K + k0 + 32 + c8],
                           &Bs[cur ^ 1][rr][0]);
            }
        }

        short8 af[4], bf[4];
        #pragma unroll
        for (int i = 0; i < 4; ++i) {
            af[i] = *(const short8*)&As[cur][wr + i * 16 + l16][quad * 8];
            bf[i] = *(const short8*)&Bs[cur][wc + i * 16 + l16][quad * 8];
        }
        #pragma unroll
        for (int mi = 0; mi < 4; ++mi)
            #pragma unroll
            for (int ni = 0; ni < 4; ++ni)
                acc[mi][ni] = __builtin_amdgcn_mfma_f32_16x16x32_bf16(
                    af[mi], bf[ni], acc[mi][ni], 0, 0, 0);
        __syncthreads();
    }

    #pragma unroll
    for (int ni = 0; ni < 4; ++ni) {
        const int col = col0 + wc + ni * 16 + l16;
        const float bs = bias[col];
        #pragma unroll
        for (int mi = 0; mi < 4; ++mi) {
            #pragma unroll
            for (int r = 0; r < 4; ++r) {
                const int row = row0 + wr + mi * 16 + quad * 4 + r;
                Cout[(size_t)row * N + col] = acc[mi][ni][r] + bs;
            }
        }
    }
}

// ===========================================================================
// Flash attention, 32x32 MFMA, zero-shuffle softmax+PV. 512 thr = 8 waves.
// (R19 verbatim -- passed at 59.5 us.)
// Wave w: qg = w&1 (32 queries), ks = w>>1 (32-key slice of 128-key tile).
// C-layout (HW-verified): col=l&31, row=(r&3)+8*(r>>2)+4*(l>>5).
// Scores: sa[r] = S^T[key=ks*32+kk(r)][q], kk(r)=(r&3)+8*(r>>2)+4*hi.
// PV slot bijection sigma_m(hi*8+j') = 4hi+(j'&3)+8*(j'>>2)+16m
//   => B-operand = own p[8m..8m+7]; A-operand = V^T[d][ks*32+sigma_m(.)]
//   = two 8B halves of 16B granules (ks*4+2m, ks*4+2m+1) at half hi.
// Swizzles (both-sides, rule 21): K granule ^(row&7); V granule ^(d&7).
// Pipeline: stage t+1 (4 DMA) -> compute t -> 1 barrier. 16 tiles.
// Epilogue: 4-way split-K combine in LDS (union with stage buffers).
// ===========================================================================
__global__ __launch_bounds__(512, 4) void attn_mfma(
    const ushort* __restrict__ Qg, const ushort* __restrict__ Kgl,
    const ushort* __restrict__ VT, ushort* __restrict__ Ctx)
{
    constexpr int S = 2048, D = 768;
    __shared__ union {
        struct {                      // main-loop stage buffers (swizzled)
            ushort Ks [2][128][64];   // [buf][key][16B-gran ^ (key&7)]
            ushort Vts[2][64][128];   // [buf][d][16B-gran ^ (d&7)]
        } s;
        struct {                      // epilogue split-K combine buffers
            float Osc[6][2048];       // [slot][lane*32 + (g^(lane&7))*4 + e]
            float Msc[6][32];
            float Lsc[6][32];
        } c;
    } U;

    const int tid  = threadIdx.x;
    const int w    = tid >> 6;        // 0..7
    const int qg   = w & 1;           // query group (32 q)
    const int ks   = w >> 1;          // key slice 0..3 (32 of 128)
    const int lane = tid & 63;
    const int l31  = lane & 31;
    const int hi   = lane >> 5;
    const int b = blockIdx.z, h = blockIdx.y, q0 = blockIdx.x * 64;
    const size_t hc = (size_t)h * 64;

    // Q fragments (B-operand): yq[dc][j'] = Q[q][dc*16 + hi*8 + j']
    const size_t qrow = (size_t)(b * S + q0 + qg * 32 + l31) * D + hc + hi * 8;
    short8 yq[4];
    #pragma unroll
    for (int dc = 0; dc < 4; ++dc) yq[dc] = *(const short8*)&Qg[qrow + dc * 16];

    // ---- staging (rule 21: pre-swizzled global source, linear LDS dest) ----
    const int sr  = tid >> 3;                    // K row 0..63 (+64 2nd issue)
    const int kgr = (tid & 7) ^ (sr & 7);        // 16B granule of 8
    const ushort* srcK = &Kgl[(size_t)(b * S + sr) * D + hc + kgr * 8];
    const int vr  = tid >> 4;                    // V row 0..31 (+32 2nd issue)
    const int vgr = (tid & 15) ^ (vr & 7);       // 16B granule of 16
    const ushort* srcV = &VT[((size_t)(b * 12 + h) * 64 + vr) * 2048 + vgr * 8];
    ushort* dK0 = &U.s.Ks [0][w * 8][0];         // wave-uniform bases
    ushort* dK1 = &U.s.Ks [1][w * 8][0];
    ushort* dV0 = &U.s.Vts[0][w * 4][0];
    ushort* dV1 = &U.s.Vts[1][w * 4][0];

    // ---- loop-invariant swizzled read offsets (ushort units) ----
    int okf[4];                                  // K b128: row ks*32+l31
    #pragma unroll
    for (int dc = 0; dc < 4; ++dc)
        okf[dc] = (ks * 32 + l31) * 64 + ((dc * 2 + hi) ^ (l31 & 7)) * 8;
    int ovo[2][2][2];                            // V b64: [a][m][chunk]
    #pragma unroll
    for (int a = 0; a < 2; ++a)
        #pragma unroll
        for (int m = 0; m < 2; ++m)
            #pragma unroll
            for (int c2 = 0; c2 < 2; ++c2)
                ovo[a][m][c2] = (a * 32 + l31) * 128 +
                    ((ks * 4 + m * 2 + c2) ^ (l31 & 7)) * 8 + hi * 4;

    float m_ = -1e30f, l_ = 0.f;
    f32x16 oa0, oa1;
    #pragma unroll
    for (int i = 0; i < 16; ++i) { oa0[i] = 0.f; oa1[i] = 0.f; }

    // prologue: stage tile 0 into buf 0
    async_cp16(srcK,                  dK0);
    async_cp16(srcK + (size_t)64 * D, dK0 + 64 * 64);
    async_cp16(srcV,                  dV0);
    async_cp16(srcV + 32 * 2048,      dV0 + 32 * 128);
    __syncthreads();                  // implicit vmcnt(0) drain

    #pragma unroll 2
    for (int t = 0; t < 16; ++t) {
        const int cur = t & 1;
        const ushort* ksb = cur ? &U.s.Ks [1][0][0] : &U.s.Ks [0][0][0];
        const ushort* vsb = cur ? &U.s.Vts[1][0][0] : &U.s.Vts[0][0][0];
        if (t + 1 < 16) {             // issue next-tile DMA before compute
            const size_t kn = (size_t)(t + 1) * 128;
            ushort* dK = cur ? dK0 : dK1;
            ushort* dV = cur ? dV0 : dV1;
            async_cp16(srcK + kn * D,              dK);
            async_cp16(srcK + (kn + 64) * D,       dK + 64 * 64);
            async_cp16(srcV + kn,                  dV);
            async_cp16(srcV + kn + 32 * 2048,      dV + 32 * 128);
        }

        // ---- scores: S^T[32k x 32q], d-chain of 4 MFMAs ----
        f32x16 sa;
        #pragma unroll
        for (int i = 0; i < 16; ++i) sa[i] = 0.f;
        __builtin_amdgcn_s_setprio(1);
        #pragma unroll
        for (int dc = 0; dc < 4; ++dc) {
            const short8 xk = *(const short8*)&ksb[okf[dc]];
            sa = __builtin_amdgcn_mfma_f32_32x32x16_bf16(xk, yq[dc], sa, 0, 0, 0);
        }
        __builtin_amdgcn_s_setprio(0);

        // ---- online softmax: 15 in-lane fmax + 1 shfl32 ----
        float mx = sa[0];
        #pragma unroll
        for (int r = 1; r < 16; ++r) mx = fmaxf(mx, sa[r]);
        mx = fmaxf(mx, __shfl_xor(mx, 32, 64));

        // defer-max (T13): rescale only when tile max outgrows m_ by >8.
        const bool full = !__all(mx - m_ <= 8.f);
        if (full) {
            const float mn = fmaxf(m_, mx);
            const float alpha = __expf(m_ - mn);   // first iter: 0
            l_ *= alpha;
            m_ = mn;
            #pragma unroll
            for (int i = 0; i < 16; ++i) { oa0[i] *= alpha; oa1[i] *= alpha; }
        }

        float p[16], ps = 0.f;
        #pragma unroll
        for (int r = 0; r < 16; ++r) {
            p[r] = __expf(sa[r] - m_);             // bounded by e^8
            ps += p[r];
        }
        ps += __shfl_xor(ps, 32, 64);
        l_ += ps;

        // ---- PV B-operands: own p[] packed (slot j' = p[8m + j']) ----
        union { unsigned u[4]; short8 s8; } pa0, pa1;
        pa0.u[0] = pk2bf(p[0],  p[1]);  pa0.u[1] = pk2bf(p[2],  p[3]);
        pa0.u[2] = pk2bf(p[4],  p[5]);  pa0.u[3] = pk2bf(p[6],  p[7]);
        pa1.u[0] = pk2bf(p[8],  p[9]);  pa1.u[1] = pk2bf(p[10], p[11]);
        pa1.u[2] = pk2bf(p[12], p[13]); pa1.u[3] = pk2bf(p[14], p[15]);

        // ---- PV: O^T[64d x 32q] += V^T x P (4 MFMAs, 8 b64 V-reads) ----
        __builtin_amdgcn_s_setprio(1);
        {
            union { uint2 v2[2]; short8 s8; } xv;
            xv.v2[0] = *(const uint2*)&vsb[ovo[0][0][0]];
            xv.v2[1] = *(const uint2*)&vsb[ovo[0][0][1]];
            oa0 = __builtin_amdgcn_mfma_f32_32x32x16_bf16(xv.s8, pa0.s8, oa0, 0, 0, 0);
            xv.v2[0] = *(const uint2*)&vsb[ovo[0][1][0]];
            xv.v2[1] = *(const uint2*)&vsb[ovo[0][1][1]];
            oa0 = __builtin_amdgcn_mfma_f32_32x32x16_bf16(xv.s8, pa1.s8, oa0, 0, 0, 0);
            xv.v2[0] = *(const uint2*)&vsb[ovo[1][0][0]];
            xv.v2[1] = *(const uint2*)&vsb[ovo[1][0][1]];
            oa1 = __builtin_amdgcn_mfma_f32_32x32x16_bf16(xv.s8, pa0.s8, oa1, 0, 0, 0);
            xv.v2[0] = *(const uint2*)&vsb[ovo[1][1][0]];
            xv.v2[1] = *(const uint2*)&vsb[ovo[1][1][1]];
            oa1 = __builtin_amdgcn_mfma_f32_32x32x16_bf16(xv.s8, pa1.s8, oa1, 0, 0, 0);
        }
        __builtin_amdgcn_s_setprio(0);

        __syncthreads();  // implicit vmcnt(0): tile t+1 staged; buf reads done
    }

    // ---- 4-way split-K combine (stage buffers dead; union reuse) ----
    if (ks > 0) {
        const int slot = (ks - 1) * 2 + qg;
        float* ob = &U.c.Osc[slot][lane * 32];
        #pragma unroll
        for (int g = 0; g < 4; ++g) {
            float4 v0, v1;
            v0.x = oa0[g * 4 + 0]; v0.y = oa0[g * 4 + 1];
            v0.z = oa0[g * 4 + 2]; v0.w = oa0[g * 4 + 3];
            v1.x = oa1[g * 4 + 0]; v1.y = oa1[g * 4 + 1];
            v1.z = oa1[g * 4 + 2]; v1.w = oa1[g * 4 + 3];
            *(float4*)&ob[(( g     ) ^ (lane & 7)) * 4] = v0;
            *(float4*)&ob[(((g + 4)) ^ (lane & 7)) * 4] = v1;
        }
        if (hi == 0) {
            U.c.Msc[slot][l31] = m_;
            U.c.Lsc[slot][l31] = l_;
        }
    }
    __syncthreads();
    if (ks == 0) {
        const float m1 = U.c.Msc[qg][l31];
        const float m2 = U.c.Msc[2 + qg][l31];
        const float m3 = U.c.Msc[4 + qg][l31];
        const float M  = fmaxf(fmaxf(m_, m1), fmaxf(m2, m3));
        const float a0 = __expf(m_ - M), a1 = __expf(m1 - M),
                    a2 = __expf(m2 - M), a3 = __expf(m3 - M);
        const float l1 = U.c.Lsc[qg][l31];
        const float l2 = U.c.Lsc[2 + qg][l31];
        const float l3 = U.c.Lsc[4 + qg][l31];
        const float inv = 1.0f / (l_ * a0 + l1 * a1 + l2 * a2 + l3 * a3);

        float o[32];
        #pragma unroll
        for (int i = 0; i < 16; ++i) { o[i] = oa0[i] * a0; o[16 + i] = oa1[i] * a0; }
        #pragma unroll
        for (int s = 0; s < 3; ++s) {
            const float as = (s == 0) ? a1 : (s == 1) ? a2 : a3;
            const float* ob = &U.c.Osc[s * 2 + qg][lane * 32];
            #pragma unroll
            for (int gg = 0; gg < 8; ++gg) {
                const float4 v = *(const float4*)&ob[(gg ^ (lane & 7)) * 4];
                o[gg * 4 + 0] += v.x * as;
                o[gg * 4 + 1] += v.y * as;
                o[gg * 4 + 2] += v.z * as;
                o[gg * 4 + 3] += v.w * as;
            }
        }

        // lane owns q = q0+qg*32+l31; d = a*32 + 8*rq + 4*hi + e
        const size_t crow = (size_t)(b * S + q0 + qg * 32 + l31) * D + hc;
        #pragma unroll
        for (int a = 0; a < 2; ++a)
            #pragma unroll
            for (int rq = 0; rq < 4; ++rq) {
                const int base = a * 16 + rq * 4;
                uint2 ov;
                ov.x = pk2bf(o[base + 0] * inv, o[base + 1] * inv);
                ov.y = pk2bf(o[base + 2] * inv, o[base + 3] * inv);
                *(uint2*)&Ctx[crow + a * 32 + rq * 8 + hi * 4] = ov;
            }
    }
}

// ===========================================================================
// Launch
// ===========================================================================
extern "C" void kernel_launch(void* const* d_in, const int* in_sizes, int n_in,
                              void* d_out, int out_size, void* d_ws, size_t ws_size,
                              hipStream_t stream)
{
    const float* x  = (const float*)d_in[0];
    const float* Wq = (const float*)d_in[1];
    const float* bq = (const float*)d_in[2];
    const float* Wk = (const float*)d_in[3];
    const float* bk = (const float*)d_in[4];
    const float* Wv = (const float*)d_in[5];
    const float* bv = (const float*)d_in[6];
    const float* Wo = (const float*)d_in[7];
    const float* bo = (const float*)d_in[8];

    const int M = 4096, D = 768;
    const size_t XE = (size_t)M * D;     // 3,145,728
    const size_t WE = (size_t)D * D;     //   589,824

    ushort* xb   = (ushort*)d_ws;
    ushort* wtq  = xb   + XE;            // wtq/wtk/wtv/wto contiguous
    ushort* wto  = wtq  + 3 * WE;
    ushort* qb   = wto  + WE;            // qb/kb/vb contiguous
    ushort* kb   = qb   + XE;
    ushort* vb   = kb   + XE;
    ushort* ctxb = vb   + XE;
    ushort* vt   = xb;                   // reuse xb (dead after fused GEMM)

    cast_f32_bf16<<<(int)(XE / 4 / 256), 256, 0, stream>>>(x, xb, (int)(XE / 4));

    transpose_cast_w4<<<dim3(12, 12, 4), 256, 0, stream>>>(Wq, Wk, Wv, Wo, wtq);

    gemm_qkv_fused<<<dim3(2304 / 128, 4096 / 128), 256, 0, stream>>>(
        xb, wtq, bq, bk, bv, qb);

    transpose_v<<<dim3(32, 12, 2), 256, 0, stream>>>(vb, vt);

    attn_mfma<<<dim3(2048 / 64, 12, 2), 512, 0, stream>>>(qb, kb, vt, ctxb);

    gemm_wo_128<<<dim3(768 / 128, 4096 / 128), 256, 0, stream>>>(
        ctxb, wto, bo, (float*)d_out);
}